// Round 15
// baseline (6118.533 us; speedup 1.0000x reference)
//
#include <hip/hip_runtime.h>
#include <cstdint>
#include <cstddef>

#define BB   64
#define SEQL 512
#define INF  512
#define HID  1024
#define GG   4096   // 4*HID

#define MU_    0.9f
#define SSTEP_ 0.1f
#define BETA_  0.999f
#define EPS_   1e-16f
#define SCL    2048.0f
#define ISCL   (1.0f / 2048.0f)

#define NWGC  64                         // consumer wgs (recurrence)
#define NWGP  128                        // producer wgs (grad GEMM + vm scan)
#define NWG_TOT (NWGC + NWGP)
#define NTHR  1024
#define WLDS  131072                     // W_hh f16 single-plane, frag order
#define RLDS  32768                      // reduce slots (hpk aliases its head)
#define SMEM_BYTES (WLDS + RLDS)         // 163840 = 160 KiB exactly

typedef unsigned short u16;
typedef unsigned int   u32;
typedef unsigned long long u64;
typedef _Float16 half8 __attribute__((ext_vector_type(8)));
typedef float f32x4 __attribute__((ext_vector_type(4)));
typedef u32 u32x4 __attribute__((ext_vector_type(4)));

__device__ __forceinline__ f32x4 mfma16(half8 a, half8 b, f32x4 c) {
  return __builtin_amdgcn_mfma_f32_16x16x32_f16(a, b, c, 0, 0, 0);
}
__device__ __forceinline__ void fsplit(float v, _Float16& hi, _Float16& lo) {
  hi = (_Float16)v;
  lo = (_Float16)((v - (float)hi) * SCL);
}
// device-coherent (cross-XCD) atomic ops (proven path)
__device__ __forceinline__ u32 coh_load32(const u32* p) {
  return __hip_atomic_load(p, __ATOMIC_RELAXED, __HIP_MEMORY_SCOPE_AGENT);
}
__device__ __forceinline__ void coh_store32(u32* p, u32 v) {
  __hip_atomic_store(p, v, __ATOMIC_RELAXED, __HIP_MEMORY_SCOPE_AGENT);
}
__device__ __forceinline__ void coh_store64(u64* p, u64 v) {
  __hip_atomic_store(p, v, __ATOMIC_RELAXED, __HIP_MEMORY_SCOPE_AGENT);
}
__device__ __forceinline__ void coh_storef(float* p, float v) {
  __hip_atomic_store(p, v, __ATOMIC_RELAXED, __HIP_MEMORY_SCOPE_AGENT);
}

// 16 batched coherent 16B loads of the tagged-h fragment (8 chunks of 32B at
// 128B stride), one asm block: un-sinkable, un-splittable.
#define GLD16(P0,P1,P2,P3,P4,P5,P6,P7,P8,P9,Pa,Pb,Pc,Pd,Pe,Pf,PA)  \
  asm volatile(                                                     \
    "global_load_dwordx4 %0, %16, off sc0 sc1\n\t"                  \
    "global_load_dwordx4 %1, %16, off offset:16 sc0 sc1\n\t"        \
    "global_load_dwordx4 %2, %16, off offset:128 sc0 sc1\n\t"       \
    "global_load_dwordx4 %3, %16, off offset:144 sc0 sc1\n\t"       \
    "global_load_dwordx4 %4, %16, off offset:256 sc0 sc1\n\t"       \
    "global_load_dwordx4 %5, %16, off offset:272 sc0 sc1\n\t"       \
    "global_load_dwordx4 %6, %16, off offset:384 sc0 sc1\n\t"       \
    "global_load_dwordx4 %7, %16, off offset:400 sc0 sc1\n\t"       \
    "global_load_dwordx4 %8, %16, off offset:512 sc0 sc1\n\t"       \
    "global_load_dwordx4 %9, %16, off offset:528 sc0 sc1\n\t"       \
    "global_load_dwordx4 %10, %16, off offset:640 sc0 sc1\n\t"      \
    "global_load_dwordx4 %11, %16, off offset:656 sc0 sc1\n\t"      \
    "global_load_dwordx4 %12, %16, off offset:768 sc0 sc1\n\t"      \
    "global_load_dwordx4 %13, %16, off offset:784 sc0 sc1\n\t"      \
    "global_load_dwordx4 %14, %16, off offset:896 sc0 sc1\n\t"      \
    "global_load_dwordx4 %15, %16, off offset:912 sc0 sc1"          \
    : "=&v"(P0), "=&v"(P1), "=&v"(P2), "=&v"(P3),                   \
      "=&v"(P4), "=&v"(P5), "=&v"(P6), "=&v"(P7),                   \
      "=&v"(P8), "=&v"(P9), "=&v"(Pa), "=&v"(Pb),                   \
      "=&v"(Pc), "=&v"(Pd), "=&v"(Pe), "=&v"(Pf)                    \
    : "v"(PA))

// 4 batched coherent dword loads (u prefetch), one asm block.
#define GLDU4(d0,d1,d2,d3,a0,a1,a2,a3)                          \
  asm volatile(                                                 \
    "global_load_dword %0, %4, off sc0 sc1\n\t"                 \
    "global_load_dword %1, %5, off sc0 sc1\n\t"                 \
    "global_load_dword %2, %6, off sc0 sc1\n\t"                 \
    "global_load_dword %3, %7, off sc0 sc1"                     \
    : "=&v"(d0), "=&v"(d1), "=&v"(d2), "=&v"(d3)                \
    : "v"(a0), "v"(a1), "v"(a2), "v"(a3))

// unpack 8 tagged u32 (low16 = f16 bits) -> half8, 4 MFMAs for one kk
#define UNPK_MFMA(W0, W1, kk)                                               \
  {                                                                         \
    union { u16 e[8]; half8 h8; } A_;                                       \
    A_.e[0] = (u16)(W0)[0]; A_.e[1] = (u16)(W0)[1];                         \
    A_.e[2] = (u16)(W0)[2]; A_.e[3] = (u16)(W0)[3];                         \
    A_.e[4] = (u16)(W1)[0]; A_.e[5] = (u16)(W1)[1];                         \
    A_.e[6] = (u16)(W1)[2]; A_.e[7] = (u16)(W1)[3];                         \
    const _Float16* wb = Wf + (size_t)((kq * 8 + (kk)) * 4) * 512 + lane * 8;\
    a0 = mfma16(A_.h8, *(const half8*)(wb), a0);                            \
    a1 = mfma16(A_.h8, *(const half8*)(wb + 512), a1);                      \
    a2 = mfma16(A_.h8, *(const half8*)(wb + 1024), a2);                     \
    a3 = mfma16(A_.h8, *(const half8*)(wb + 1536), a3);                     \
  }

// ---- transpose + f16-split: src [R][C] f32 -> dhi/dlo [C][R] f16 ----
__global__ __launch_bounds__(256) void transpose_split(const float* __restrict__ src,
                                                       _Float16* __restrict__ dhi,
                                                       _Float16* __restrict__ dlo,
                                                       int R, int C) {
  __shared__ float tile[32][33];
  int c0 = blockIdx.x * 32, r0 = blockIdx.y * 32;
  int tx = threadIdx.x & 31, ty = threadIdx.x >> 5;
#pragma unroll
  for (int i = 0; i < 32; i += 8)
    tile[ty + i][tx] = src[(size_t)(r0 + ty + i) * C + (c0 + tx)];
  __syncthreads();
#pragma unroll
  for (int i = 0; i < 32; i += 8) {
    float v = tile[tx][ty + i];
    _Float16 hi, lo;
    fsplit(v, hi, lo);
    size_t o = (size_t)(c0 + ty + i) * R + (r0 + tx);
    dhi[o] = hi;
    dlo[o] = lo;
  }
}

// ---- pre-split x: f32 [B*S][IN] -> f16 [B*S][2][IN] (hi plane, lo plane) ----
__global__ __launch_bounds__(256) void split_x(const float* __restrict__ x,
                                               _Float16* __restrict__ xs) {
  size_t i = (size_t)blockIdx.x * 256 + threadIdx.x;   // one 8-elem chunk
  size_t e = i * 8;
  size_t r = e / INF, col = e % INF;
  f32x4 v0 = *(const f32x4*)(x + e);
  f32x4 v1 = *(const f32x4*)(x + e + 4);
  half8 hi, lo;
#pragma unroll
  for (int j = 0; j < 4; j++) {
    _Float16 h_, l_;
    fsplit(v0[j], h_, l_); hi[j] = h_; lo[j] = l_;
    fsplit(v1[j], h_, l_); hi[4 + j] = h_; lo[4 + j] = l_;
  }
  _Float16* dst = xs + r * 2 * INF + col;
  *(half8*)(dst) = hi;
  *(half8*)(dst + INF) = lo;
}

// ---- init running state: h -> TAGGED u32 planes (tag 0 in buf0, invalid in buf1)
__global__ __launch_bounds__(256) void init_state(const float* __restrict__ h0,
                                                  const float* __restrict__ c0,
                                                  const float* __restrict__ v0,
                                                  const float* __restrict__ m0,
                                                  float* __restrict__ co,
                                                  float* __restrict__ vo,
                                                  float* __restrict__ mo,
                                                  u32* __restrict__ hT0,
                                                  u32* __restrict__ hT1) {
  int i = blockIdx.x * 256 + threadIdx.x;
  if (i < BB * GG) { vo[i] = v0[i]; mo[i] = m0[i]; }
  if (i < BB * HID) {
    co[i] = c0[i];
    u16 hb = __builtin_bit_cast(u16, (_Float16)h0[i]);
    hT0[i] = (u32)hb;        // tag 0 (h index 0)
    hT1[i] = 0xFFFF0000u;    // invalid tag (kills cross-replay stale collision)
  }
}

// ---- FUSED persistent kernel: 192 wgs x 1024 thr ----
// Consumers (0..63): recurrence with TAG-EMBEDDED h handoff — h stored as
//   u32 = f16bits | (h_index<<16); reader retries until all 64 tags match.
//   No flag store, no flag poll, no store drain: sync fused into data RT.
//   K=2 buffer safety: wg stores h[s+1] only after h[s] reads RETURNED; any
//   h[s+2] write needs all h[s+1] reads -> all h[s] reads complete. QED.
// Producers (64..191): unchanged from r14 (proven).
__global__ __attribute__((amdgpu_flat_work_group_size(NTHR, NTHR),
                          amdgpu_waves_per_eu(4, 4))) void rnn_fused(
    const _Float16* __restrict__ xs,      // [B*S][2][IN]
    const _Float16* __restrict__ whi,     // W_ih^T hi [G][IN]
    const _Float16* __restrict__ wlo,     // W_ih^T lo [G][IN]
    const float* __restrict__ bih,
    float* __restrict__ u,                // [T][B][G] produced in-kernel
    const _Float16* __restrict__ whh_hi,  // [G][H] f16
    const float* __restrict__ bhh,
    u32* __restrict__ hTA, u32* __restrict__ hTB,  // tagged h planes
    float* __restrict__ lout, float* __restrict__ hout,
    float* __restrict__ cout,             // running c
    float* __restrict__ vst, float* __restrict__ mst,  // running v,m
    u32* __restrict__ flags, int t0, int T) {
  extern __shared__ char smem[];
  int tid = threadIdx.x;
  int wave = tid >> 6, lane = tid & 63;
  int l15 = lane & 15, lg = lane >> 4;

  if (blockIdx.x < NWGC) {
    // ================= CONSUMER =================
    _Float16* Wf = (_Float16*)smem;               // 128 KiB frag-order weights
    float* red = (float*)(smem + WLDS);           // [bt4][kqh2][rt4][col16][16]
    u32* hpk = (u32*)(smem + WLDS);               // aliases red head (sync-guarded)
    int bt = wave >> 2, kq = wave & 3;
    int nb = blockIdx.x;

    // stage W_hh slice into LDS in fragment order
    for (int s = tid; s < 8192; s += NTHR) {
      int ln = s & 63, rest = s >> 6;
      int rt = rest & 3, kk = (rest >> 2) & 7, kq2 = rest >> 5;
      int grow = rt * HID + nb * 16 + (ln & 15);
      int k = kq2 * 256 + kk * 32 + (ln >> 4) * 8;
      *(half8*)(Wf + (size_t)s * 8) = *(const half8*)(whh_hi + (size_t)grow * HID + k);
    }

    // epilogue constants: thread = (batch bo, cell j)
    int bo = tid >> 4, j = tid & 15;
    int en = nb * 16 + j;
    int within = bo & 15, btE = bo >> 4;
    int wsl = (((within >> 2) + j) & 3) * 4 + (within & 3);  // de-swizzle slot
    float bh_[4], creg;
#pragma unroll
    for (int q = 0; q < 4; q++) bh_[q] = bhh[q * HID + en];
    creg = cout[(size_t)bo * HID + en];
    // tagged-h fragment byte offset for this lane's GEMM A-row (u32 elems x4)
    u64 hOffB = (u64)(((bt * 16 + l15) * HID + kq * 256 + lg * 8) * 4);
    u64 hTA_ = (u64)(uintptr_t)hTA + hOffB;
    u64 hTB_ = (u64)(uintptr_t)hTB + hOffB;
    // tagged-h store mapping (tid<512): row sb, u64 pair ss
    int sb = tid >> 3, ss = tid & 7;
    u64* wA = (u64*)(hTA + (size_t)sb * HID + nb * 16) + ss;
    u64* wB = (u64*)(hTB + (size_t)sb * HID + nb * 16) + ss;
    // per-thread u base address (q=0 gate)
    u64 ubT = (u64)(uintptr_t)u + (((size_t)bo * GG) + en) * 4;
    __syncthreads();

    // preamble: wait producers for u[t0..t0+1]
    if (wave == 0) {
      u32 tp = (u32)(t0 + (T < 2 ? T : 2));
      const u32* p0 = flags + (size_t)(NWGC + 2 * lane) * 32;
      while (!__all(coh_load32(p0) >= tp && coh_load32(p0 + 32) >= tp))
        __builtin_amdgcn_s_sleep(1);
    }
    __syncthreads();
    float uvA, uvB, uvC, uvD;
    GLDU4(uvA, uvB, uvC, uvD, ubT, ubT + 4096, ubT + 8192, ubT + 12288);
    asm volatile("s_waitcnt vmcnt(0)"
                 : "+v"(uvA), "+v"(uvB), "+v"(uvC), "+v"(uvD) :: "memory");
    float uv[4] = {uvA, uvB, uvC, uvD};

    for (int tt = 0; tt < T; ++tt) {
      int gt = t0 + tt;
      u64 rB = (gt & 1) ? hTB_ : hTA_;
      u32 key = ((u32)gt & 0xFFFFu) << 16;
      u32x4 key4 = {key, key, key, key};

      // ---- tagged h load with retry (sync fused into the data round trip)
      u32x4 T0, T1, T2, T3, T4, T5, T6, T7, T8, T9, Ta, Tb, Tc_, Td, Te, Tf;
      while (true) {
        GLD16(T0, T1, T2, T3, T4, T5, T6, T7, T8, T9, Ta, Tb, Tc_, Td, Te, Tf, rB);
        asm volatile("s_waitcnt vmcnt(0)" ::: "memory");
        __builtin_amdgcn_sched_barrier(0);
        u32x4 b4 = (T0 ^ key4) | (T1 ^ key4) | (T2 ^ key4) | (T3 ^ key4) |
                   (T4 ^ key4) | (T5 ^ key4) | (T6 ^ key4) | (T7 ^ key4) |
                   (T8 ^ key4) | (T9 ^ key4) | (Ta ^ key4) | (Tb ^ key4) |
                   (Tc_ ^ key4) | (Td ^ key4) | (Te ^ key4) | (Tf ^ key4);
        u32 bad = (b4[0] | b4[1] | b4[2] | b4[3]) >> 16;
        if (__all(bad == 0)) break;
        __builtin_amdgcn_s_sleep(1);
      }
      // issue next-step u prefetch early (safe: last step's wave-1 poll
      // guaranteed u[tt+1] stored before this step began)
      float uvN0 = 0, uvN1 = 0, uvN2 = 0, uvN3 = 0;
      if (tt + 1 < T) {
        u64 ubn = ubT + ((u64)(tt + 1) * ((u64)BB * GG * 4));
        GLDU4(uvN0, uvN1, uvN2, uvN3, ubn, ubn + 4096, ubn + 8192, ubn + 12288);
      }

      f32x4 a0 = {}, a1 = {}, a2 = {}, a3 = {};
      UNPK_MFMA(T0, T1, 0) UNPK_MFMA(T2, T3, 1)
      UNPK_MFMA(T4, T5, 2) UNPK_MFMA(T6, T7, 3)
      UNPK_MFMA(T8, T9, 4) UNPK_MFMA(Ta, Tb, 5)
      UNPK_MFMA(Tc_, Td, 6) UNPK_MFMA(Te, Tf, 7)

      // producer-progress poll, piggybacked on wave 1 (ordered by reduce sync)
      if (wave == 1) {
        u32 t2 = (u32)(t0 + (tt + 3 < T ? tt + 3 : T));
        const u32* p0 = flags + (size_t)(NWGC + 2 * lane) * 32;
        while (!__all(coh_load32(p0) >= t2 && coh_load32(p0 + 32) >= t2))
          __builtin_amdgcn_s_sleep(1);
      }

      // pairwise kq reduce in LDS, granule-rotation swizzled
      int kqh = kq >> 1;
      int p = (lg + l15) & 3;
      int sB0 = (((bt * 2 + kqh) * 4 + 0) * 16 + l15) * 16 + p * 4;
      int sB1 = (((bt * 2 + kqh) * 4 + 1) * 16 + l15) * 16 + p * 4;
      int sB2 = (((bt * 2 + kqh) * 4 + 2) * 16 + l15) * 16 + p * 4;
      int sB3 = (((bt * 2 + kqh) * 4 + 3) * 16 + l15) * 16 + p * 4;
      if (kq & 1) {
        *(f32x4*)(red + sB0) = a0;
        *(f32x4*)(red + sB1) = a1;
        *(f32x4*)(red + sB2) = a2;
        *(f32x4*)(red + sB3) = a3;
      }
      __syncthreads();
      if (!(kq & 1)) {
        *(f32x4*)(red + sB0) = a0 + *(const f32x4*)(red + sB0);
        *(f32x4*)(red + sB1) = a1 + *(const f32x4*)(red + sB1);
        *(f32x4*)(red + sB2) = a2 + *(const f32x4*)(red + sB2);
        *(f32x4*)(red + sB3) = a3 + *(const f32x4*)(red + sB3);
      }
      __syncthreads();

      // epilogue: all 1024 threads
      float gate[4];
#pragma unroll
      for (int q = 0; q < 4; q++) {
        float rec = red[(((btE * 2 + 0) * 4 + q) * 16 + j) * 16 + wsl] +
                    red[(((btE * 2 + 1) * 4 + q) * 16 + j) * 16 + wsl];
        gate[q] = uv[q] + rec + bh_[q];
      }
      // rotate u prefetch (dep-carried wait; only uvN outstanding here)
      asm volatile("s_waitcnt vmcnt(0)"
                   : "+v"(uvN0), "+v"(uvN1), "+v"(uvN2), "+v"(uvN3) :: "memory");
      uv[0] = uvN0; uv[1] = uvN1; uv[2] = uvN2; uv[3] = uvN3;

      float ig = 1.0f / (1.0f + expf(-gate[0]));
      float fg = 1.0f / (1.0f + expf(-gate[1]));
      float gg = tanhf(gate[2]);
      float og = 1.0f / (1.0f + expf(-gate[3]));
      creg = creg * fg + ig * gg;
      float hh = og * tanhf(creg);
      __syncthreads();  // all red reads done before hpk (aliased) is written

      lout[((size_t)bo * SEQL + gt) * HID + en] = hh;
      hpk[bo * 16 + j] = (u32)__builtin_bit_cast(u16, (_Float16)hh) |
                         ((u32)((gt + 1) & 0xFFFF) << 16);
      if (gt == SEQL - 1) hout[(size_t)bo * HID + en] = hh;
      if (tt == T - 1)    cout[(size_t)bo * HID + en] = creg;
      __syncthreads();  // h pack complete

      // tagged h stores: 512 x u64 (no drain, no flags — tags carry the sync)
      if (tid < 512) {
        u64 val = *(const u64*)(hpk + sb * 16 + ss * 2);
        coh_store64((gt & 1) ? wA : wB, val);
      }
    }
  } else {
    // ================= PRODUCER (unchanged, proven) =================
    float* pred = (float*)smem;  // [kh2][nt8][col16][row16] f32 = 16 KiB
    int pid = blockIdx.x - NWGC;
    int btp = pid & 3;
    int n0 = (pid >> 2) * 128;
    int nt = wave & 7, kh = wave >> 3;

    const _Float16* xa = xs + (size_t)(btp * 16 + l15) * SEQL * (2 * INF)
                            + kh * 256 + lg * 8;
    const _Float16* whp = whi + (size_t)(n0 + nt * 16 + l15) * INF + kh * 256 + lg * 8;
    const _Float16* wlp = wlo + (size_t)(n0 + nt * 16 + l15) * INF + kh * 256 + lg * 8;
    float* pp = pred + (((kh * 8 + nt) * 16 + l15) * 16 + lg * 4);

    int b_l = tid >> 6, g_l = tid & 63;
    int bg = btp * 16 + b_l;
    int g0 = n0 + g_l, g1 = n0 + g_l + 64;
    size_t gi0 = (size_t)bg * GG + g0, gi1 = (size_t)bg * GG + g1;
    float vr0 = vst[gi0], vr1 = vst[gi1];
    float mr0 = mst[gi0], mr1 = mst[gi1];
    float bi0 = bih[g0], bi1 = bih[g1];
    int nt0 = g_l >> 4, c0i = g_l & 15;
    int nt1 = (g_l + 64) >> 4, c1i = g_l & 15;
    __syncthreads();

    for (int tt = 0; tt < T; ++tt) {
      const _Float16* xt = xa + (size_t)(t0 + tt) * (2 * INF);
      f32x4 aM = {}, aL = {};
#pragma unroll
      for (int kk = 0; kk < 256; kk += 32) {
        half8 ah = *(const half8*)(xt + kk);
        half8 al = *(const half8*)(xt + INF + kk);
        half8 bh = *(const half8*)(whp + kk);
        half8 bl = *(const half8*)(wlp + kk);
        aM = mfma16(ah, bh, aM);
        aL = mfma16(al, bh, aL);
        aL = mfma16(ah, bl, aL);
      }
      f32x4 cb;
#pragma unroll
      for (int i2 = 0; i2 < 4; ++i2) cb[i2] = aM[i2] + aL[i2] * ISCL;
      *(f32x4*)pp = cb;
      __syncthreads();

      float rec0 = pred[((0 + nt0) * 16 + c0i) * 16 + b_l] +
                   pred[((8 + nt0) * 16 + c0i) * 16 + b_l];
      float rec1 = pred[((0 + nt1) * 16 + c1i) * 16 + b_l] +
                   pred[((8 + nt1) * 16 + c1i) * 16 + b_l];
      float gr0 = rec0 + bi0, gr1 = rec1 + bi1;
      vr0 = MU_ * vr0 + SSTEP_ * gr0;
      mr0 = BETA_ * mr0 + (1.0f - BETA_) * gr0 * gr0;
      vr1 = MU_ * vr1 + SSTEP_ * gr1;
      mr1 = BETA_ * mr1 + (1.0f - BETA_) * gr1 * gr1;
      float* ub = u + ((size_t)tt * BB + bg) * GG;
      coh_storef(ub + g0, vr0 / (sqrtf(mr0) + EPS_));
      coh_storef(ub + g1, vr1 / (sqrtf(mr1) + EPS_));
      if (tt == T - 1) {
        vst[gi0] = vr0; vst[gi1] = vr1;
        mst[gi0] = mr0; mst[gi1] = mr1;
      }
      asm volatile("s_waitcnt vmcnt(0)" ::: "memory");  // u stores drained
      __syncthreads();
      if (tid == 0)
        coh_store32(flags + (size_t)(NWGC + pid) * 32, (u32)(t0 + tt + 1));
    }
  }
}

extern "C" void kernel_launch(void* const* d_in, const int* in_sizes, int n_in,
                              void* d_out, int out_size, void* d_ws, size_t ws_size,
                              hipStream_t stream) {
  const float* x   = (const float*)d_in[0];
  const float* wih = (const float*)d_in[1];
  const float* whh = (const float*)d_in[2];
  const float* bih = (const float*)d_in[3];
  const float* bhh = (const float*)d_in[4];
  const float* h0  = (const float*)d_in[5];
  const float* c0  = (const float*)d_in[6];
  const float* v0  = (const float*)d_in[7];
  const float* m0  = (const float*)d_in[8];

  float* out  = (float*)d_out;
  float* lout = out;
  float* hout = out + (size_t)BB * SEQL * HID;
  float* cout = hout + (size_t)BB * HID;   // running c
  float* vout = cout + (size_t)BB * HID;   // running v
  float* mout = vout + (size_t)BB * GG;    // running m

  char* ws = (char*)d_ws;
  size_t o = 0;
  _Float16* wih_hi = (_Float16*)(ws + o); o += (size_t)GG * INF * 2;
  _Float16* wih_lo = (_Float16*)(ws + o); o += (size_t)GG * INF * 2;
  _Float16* whh_hi = (_Float16*)(ws + o); o += (size_t)GG * HID * 2;
  _Float16* whh_lo = (_Float16*)(ws + o); o += (size_t)GG * HID * 2;  // staging only
  _Float16* xs     = (_Float16*)(ws + o); o += (size_t)BB * SEQL * 2 * INF * 2;  // 64 MiB
  u32* hTA = (u32*)(ws + o); o += (size_t)BB * HID * 4;   // tagged h buf0, 256 KiB
  u32* hTB = (u32*)(ws + o); o += (size_t)BB * HID * 4;   // tagged h buf1
  o = (o + 255) & ~(size_t)255;
  u32* flags = (u32*)(ws + o); o += (size_t)NWG_TOT * 32 * 4;
  float* U = (float*)(ws + o);

  const size_t STEP_BYTES = (size_t)BB * GG * sizeof(float);
  size_t cap = (ws_size > o) ? (ws_size - o) / STEP_BYTES : 1;
  if (cap < 1) cap = 1;
  int Tc = (int)(cap < (size_t)SEQL ? cap : (size_t)SEQL);

  split_x<<<(BB * SEQL * INF / 8) / 256, 256, 0, stream>>>(x, xs);
  transpose_split<<<dim3(GG / 32, INF / 32), 256, 0, stream>>>(wih, wih_hi, wih_lo, INF, GG);
  transpose_split<<<dim3(GG / 32, HID / 32), 256, 0, stream>>>(whh, whh_hi, whh_lo, HID, GG);
  init_state<<<(BB * GG) / 256, 256, 0, stream>>>(h0, c0, v0, m0, cout, vout, mout, hTA, hTB);
  hipMemsetAsync(flags, 0, (size_t)NWG_TOT * 32 * 4, stream);

  for (int t0 = 0; t0 < SEQL; t0 += Tc) {
    int T = (SEQL - t0 < Tc) ? (SEQL - t0) : Tc;
    rnn_fused<<<NWG_TOT, NTHR, SMEM_BYTES, stream>>>(
        xs, wih_hi, wih_lo, bih, U, whh_hi, bhh,
        hTA, hTB, lout, hout, cout, vout, mout, flags, t0, T);
  }
}

// Round 16
// 4584.716 us; speedup vs baseline: 1.3345x; 1.3345x over previous
//
#include <hip/hip_runtime.h>
#include <cstdint>
#include <cstddef>

#define BB   64
#define SEQL 512
#define INF  512
#define HID  1024
#define GG   4096   // 4*HID

#define MU_    0.9f
#define SSTEP_ 0.1f
#define BETA_  0.999f
#define EPS_   1e-16f
#define SCL    2048.0f
#define ISCL   (1.0f / 2048.0f)

#define NWGC  64                         // consumer wgs (recurrence)
#define NWGP  128                        // producer wgs (grad GEMM + vm scan)
#define NWG_TOT (NWGC + NWGP)
#define NTHR  1024
#define WLDS  131072                     // W_hh f16 single-plane, frag order
#define RLDS  32768                      // reduce slots
#define SMEM_BYTES (WLDS + RLDS)         // 163840 = 160 KiB exactly

typedef unsigned short u16;
typedef unsigned int   u32;
typedef unsigned long long u64;
typedef _Float16 half8 __attribute__((ext_vector_type(8)));
typedef float f32x4 __attribute__((ext_vector_type(4)));
typedef u32 u32x4 __attribute__((ext_vector_type(4)));

__device__ __forceinline__ f32x4 mfma16(half8 a, half8 b, f32x4 c) {
  return __builtin_amdgcn_mfma_f32_16x16x32_f16(a, b, c, 0, 0, 0);
}
__device__ __forceinline__ void fsplit(float v, _Float16& hi, _Float16& lo) {
  hi = (_Float16)v;
  lo = (_Float16)((v - (float)hi) * SCL);
}
// device-coherent (cross-XCD) atomic ops (proven path)
__device__ __forceinline__ u32 coh_load32(const u32* p) {
  return __hip_atomic_load(p, __ATOMIC_RELAXED, __HIP_MEMORY_SCOPE_AGENT);
}
__device__ __forceinline__ void coh_store32(u32* p, u32 v) {
  __hip_atomic_store(p, v, __ATOMIC_RELAXED, __HIP_MEMORY_SCOPE_AGENT);
}
__device__ __forceinline__ void coh_store64(u64* p, u64 v) {
  __hip_atomic_store(p, v, __ATOMIC_RELAXED, __HIP_MEMORY_SCOPE_AGENT);
}
__device__ __forceinline__ void coh_storef(float* p, float v) {
  __hip_atomic_store(p, v, __ATOMIC_RELAXED, __HIP_MEMORY_SCOPE_AGENT);
}

// 8 batched device-coherent 16B loads from base addr (+ kk*64B), one asm block.
#define GLD8(o0,o1,o2,o3,o4,o5,o6,o7,addr)                      \
  asm volatile(                                                 \
    "global_load_dwordx4 %0, %8, off sc0 sc1\n\t"               \
    "global_load_dwordx4 %1, %8, off offset:64 sc0 sc1\n\t"     \
    "global_load_dwordx4 %2, %8, off offset:128 sc0 sc1\n\t"    \
    "global_load_dwordx4 %3, %8, off offset:192 sc0 sc1\n\t"    \
    "global_load_dwordx4 %4, %8, off offset:256 sc0 sc1\n\t"    \
    "global_load_dwordx4 %5, %8, off offset:320 sc0 sc1\n\t"    \
    "global_load_dwordx4 %6, %8, off offset:384 sc0 sc1\n\t"    \
    "global_load_dwordx4 %7, %8, off offset:448 sc0 sc1"        \
    : "=&v"(o0), "=&v"(o1), "=&v"(o2), "=&v"(o3),               \
      "=&v"(o4), "=&v"(o5), "=&v"(o6), "=&v"(o7)                \
    : "v"(addr))

// 4 batched coherent dword loads (u prefetch), one asm block.
#define GLDU4(d0,d1,d2,d3,a0,a1,a2,a3)                          \
  asm volatile(                                                 \
    "global_load_dword %0, %4, off sc0 sc1\n\t"                 \
    "global_load_dword %1, %5, off sc0 sc1\n\t"                 \
    "global_load_dword %2, %6, off sc0 sc1\n\t"                 \
    "global_load_dword %3, %7, off sc0 sc1"                     \
    : "=&v"(d0), "=&v"(d1), "=&v"(d2), "=&v"(d3)                \
    : "v"(a0), "v"(a1), "v"(a2), "v"(a3))

// MFMA cluster for one kk: h fragment x 4 rt weight tiles (gates 0..3).
#define HIMF(Hk, kk)                                                        \
  {                                                                         \
    half8 ah = __builtin_bit_cast(half8, Hk);                               \
    const _Float16* wb = Wf + (size_t)((kq * 8 + (kk)) * 4) * 512 + lane * 8;\
    a0 = mfma16(ah, *(const half8*)(wb), a0);                               \
    a1 = mfma16(ah, *(const half8*)(wb + 512), a1);                         \
    a2 = mfma16(ah, *(const half8*)(wb + 1024), a2);                        \
    a3 = mfma16(ah, *(const half8*)(wb + 1536), a3);                        \
  }

// ---- transpose + f16-split: src [R][C] f32 -> dhi/dlo [C][R] f16 ----
__global__ __launch_bounds__(256) void transpose_split(const float* __restrict__ src,
                                                       _Float16* __restrict__ dhi,
                                                       _Float16* __restrict__ dlo,
                                                       int R, int C) {
  __shared__ float tile[32][33];
  int c0 = blockIdx.x * 32, r0 = blockIdx.y * 32;
  int tx = threadIdx.x & 31, ty = threadIdx.x >> 5;
#pragma unroll
  for (int i = 0; i < 32; i += 8)
    tile[ty + i][tx] = src[(size_t)(r0 + ty + i) * C + (c0 + tx)];
  __syncthreads();
#pragma unroll
  for (int i = 0; i < 32; i += 8) {
    float v = tile[tx][ty + i];
    _Float16 hi, lo;
    fsplit(v, hi, lo);
    size_t o = (size_t)(c0 + ty + i) * R + (r0 + tx);
    dhi[o] = hi;
    dlo[o] = lo;
  }
}

// ---- pre-split x: f32 [B*S][IN] -> f16 [B*S][2][IN] (hi plane, lo plane) ----
__global__ __launch_bounds__(256) void split_x(const float* __restrict__ x,
                                               _Float16* __restrict__ xs) {
  size_t i = (size_t)blockIdx.x * 256 + threadIdx.x;   // one 8-elem chunk
  size_t e = i * 8;
  size_t r = e / INF, col = e % INF;
  f32x4 v0 = *(const f32x4*)(x + e);
  f32x4 v1 = *(const f32x4*)(x + e + 4);
  half8 hi, lo;
#pragma unroll
  for (int j = 0; j < 4; j++) {
    _Float16 h_, l_;
    fsplit(v0[j], h_, l_); hi[j] = h_; lo[j] = l_;
    fsplit(v1[j], h_, l_); hi[4 + j] = h_; lo[4 + j] = l_;
  }
  _Float16* dst = xs + r * 2 * INF + col;
  *(half8*)(dst) = hi;
  *(half8*)(dst + INF) = lo;
}

// ---- init running state (h -> single f16 plane) ----
__global__ __launch_bounds__(256) void init_state(const float* __restrict__ h0,
                                                  const float* __restrict__ c0,
                                                  const float* __restrict__ v0,
                                                  const float* __restrict__ m0,
                                                  float* __restrict__ co,
                                                  float* __restrict__ vo,
                                                  float* __restrict__ mo,
                                                  _Float16* __restrict__ hhi) {
  int i = blockIdx.x * 256 + threadIdx.x;
  if (i < BB * GG) { vo[i] = v0[i]; mo[i] = m0[i]; }
  if (i < BB * HID) {
    co[i] = c0[i];
    hhi[i] = (_Float16)h0[i];
  }
}

// ---- FUSED persistent kernel: 192 wgs x 1024 thr (r14 structure, proven) ----
// wgs 0..63  : consumers — recurrence; h stored via SHFL-PACK (no LDS alias,
//              2 fewer barriers/step than r14's hpk path; h bits identical).
// wgs 64..191: producers — grad GEMM + v/m scan, byte-identical to r14.
__global__ __attribute__((amdgpu_flat_work_group_size(NTHR, NTHR),
                          amdgpu_waves_per_eu(4, 4))) void rnn_fused(
    const _Float16* __restrict__ xs,      // [B*S][2][IN]
    const _Float16* __restrict__ whi,     // W_ih^T hi [G][IN]
    const _Float16* __restrict__ wlo,     // W_ih^T lo [G][IN]
    const float* __restrict__ bih,
    float* __restrict__ u,                // [T][B][G] produced in-kernel
    const _Float16* __restrict__ whh_hi,  // [G][H] f16
    const float* __restrict__ bhh,
    _Float16* __restrict__ hA, _Float16* __restrict__ hB,
    float* __restrict__ lout, float* __restrict__ hout,
    float* __restrict__ cout,             // running c
    float* __restrict__ vst, float* __restrict__ mst,  // running v,m
    u32* __restrict__ flags, int t0, int T) {
  extern __shared__ char smem[];
  int tid = threadIdx.x;
  int wave = tid >> 6, lane = tid & 63;
  int l15 = lane & 15, lg = lane >> 4;

  if (blockIdx.x < NWGC) {
    // ================= CONSUMER =================
    _Float16* Wf = (_Float16*)smem;               // 128 KiB frag-order weights
    float* red = (float*)(smem + WLDS);           // [bt4][kqh2][rt4][col16][16]
    int bt = wave >> 2, kq = wave & 3;
    int nb = blockIdx.x;

    // stage W_hh slice into LDS in fragment order
    for (int s = tid; s < 8192; s += NTHR) {
      int ln = s & 63, rest = s >> 6;
      int rt = rest & 3, kk = (rest >> 2) & 7, kq2 = rest >> 5;
      int grow = rt * HID + nb * 16 + (ln & 15);
      int k = kq2 * 256 + kk * 32 + (ln >> 4) * 8;
      *(half8*)(Wf + (size_t)s * 8) = *(const half8*)(whh_hi + (size_t)grow * HID + k);
    }

    // epilogue constants: thread = (batch bo, cell j)
    int bo = tid >> 4, j = tid & 15;
    int en = nb * 16 + j;
    int within = bo & 15, btE = bo >> 4;
    int wsl = (((within >> 2) + j) & 3) * 4 + (within & 3);  // de-swizzle slot
    float bh_[4], creg;
#pragma unroll
    for (int q = 0; q < 4; q++) bh_[q] = bhh[q * HID + en];
    creg = cout[(size_t)bo * HID + en];
    // h fragment byte offset for this lane's GEMM A-row
    u64 hOffB = (u64)(((bt * 16 + l15) * HID + kq * 256 + lg * 8) * 2);
    u64 hAB = (u64)(uintptr_t)hA + hOffB;
    u64 hBB = (u64)(uintptr_t)hB + hOffB;
    // shfl-pack h store targets: thread (bo, j), j%4==0 stores u64 of 4 cells
    u64* wSA = (u64*)(hA + (size_t)bo * HID + nb * 16) + (j >> 2);
    u64* wSB = (u64*)(hB + (size_t)bo * HID + nb * 16) + (j >> 2);
    // per-thread u base address (q=0 gate)
    u64 ubT = (u64)(uintptr_t)u + (((size_t)bo * GG) + en) * 4;
    __syncthreads();

    // wait for producers: u[t0] and u[t0+1]
    if (wave == 0) {
      u32 tp = (u32)(t0 + (T < 2 ? T : 2));
      const u32* p0 = flags + (size_t)(NWGC + 2 * lane) * 32;
      while (!__all(coh_load32(p0) >= tp && coh_load32(p0 + 32) >= tp))
        __builtin_amdgcn_s_sleep(1);
    }
    __syncthreads();
    float uvA, uvB, uvC, uvD;
    GLDU4(uvA, uvB, uvC, uvD, ubT, ubT + 4096, ubT + 8192, ubT + 12288);
    asm volatile("s_waitcnt vmcnt(0)"
                 : "+v"(uvA), "+v"(uvB), "+v"(uvC), "+v"(uvD) :: "memory");
    float uv[4] = {uvA, uvB, uvC, uvD};

    for (int tt = 0; tt < T; ++tt) {
      int gt = t0 + tt;
      u64 rB = (gt & 1) ? hBB : hAB;

      u32x4 H0, H1, H2, H3, H4, H5, H6, H7;
      GLD8(H0, H1, H2, H3, H4, H5, H6, H7, rB);
      asm volatile("s_waitcnt vmcnt(0)" ::: "memory");   // h landed
      __builtin_amdgcn_sched_barrier(0);

      f32x4 a0 = {}, a1 = {}, a2 = {}, a3 = {};
      HIMF(H0, 0) HIMF(H1, 1) HIMF(H2, 2) HIMF(H3, 3)
      HIMF(H4, 4) HIMF(H5, 5) HIMF(H6, 6) HIMF(H7, 7)

      // pairwise kq reduce in LDS, granule-rotation swizzled
      int kqh = kq >> 1;
      int p = (lg + l15) & 3;
      int sB0 = (((bt * 2 + kqh) * 4 + 0) * 16 + l15) * 16 + p * 4;
      int sB1 = (((bt * 2 + kqh) * 4 + 1) * 16 + l15) * 16 + p * 4;
      int sB2 = (((bt * 2 + kqh) * 4 + 2) * 16 + l15) * 16 + p * 4;
      int sB3 = (((bt * 2 + kqh) * 4 + 3) * 16 + l15) * 16 + p * 4;
      if (kq & 1) {
        *(f32x4*)(red + sB0) = a0;
        *(f32x4*)(red + sB1) = a1;
        *(f32x4*)(red + sB2) = a2;
        *(f32x4*)(red + sB3) = a3;
      }
      __syncthreads();
      if (!(kq & 1)) {
        *(f32x4*)(red + sB0) = a0 + *(const f32x4*)(red + sB0);
        *(f32x4*)(red + sB1) = a1 + *(const f32x4*)(red + sB1);
        *(f32x4*)(red + sB2) = a2 + *(const f32x4*)(red + sB2);
        *(f32x4*)(red + sB3) = a3 + *(const f32x4*)(red + sB3);
      }
      // coherent prefetch of next step's u
      float uvN0 = 0, uvN1 = 0, uvN2 = 0, uvN3 = 0;
      if (tt + 1 < T) {
        u64 ubn = ubT + ((u64)(tt + 1) * ((u64)BB * GG * 4));
        GLDU4(uvN0, uvN1, uvN2, uvN3, ubn, ubn + 4096, ubn + 8192, ubn + 12288);
      }
      __syncthreads();

      // epilogue: all 1024 threads; no LDS alias, no extra barriers
      float gate[4];
#pragma unroll
      for (int q = 0; q < 4; q++) {
        float rec = red[(((btE * 2 + 0) * 4 + q) * 16 + j) * 16 + wsl] +
                    red[(((btE * 2 + 1) * 4 + q) * 16 + j) * 16 + wsl];
        gate[q] = uv[q] + rec + bh_[q];
      }
      float ig = 1.0f / (1.0f + expf(-gate[0]));
      float fg = 1.0f / (1.0f + expf(-gate[1]));
      float gg = tanhf(gate[2]);
      float og = 1.0f / (1.0f + expf(-gate[3]));
      creg = creg * fg + ig * gg;
      float hh = og * tanhf(creg);

      lout[((size_t)bo * SEQL + gt) * HID + en] = hh;
      if (gt == SEQL - 1) hout[(size_t)bo * HID + en] = hh;
      if (tt == T - 1)    cout[(size_t)bo * HID + en] = creg;

      // shfl-pack h -> 256 coherent u64 stores (bits identical to r14 path)
      u32 myh = (u32)__builtin_bit_cast(u16, (_Float16)hh);
      u32 oh = __shfl_xor(myh, 1);
      u32 ph = (j & 1) ? (oh | (myh << 16)) : (myh | (oh << 16));
      u32 qh = __shfl_xor(ph, 2);
      if ((j & 3) == 0)
        coh_store64((gt & 1) ? wSA : wSB, (u64)ph | ((u64)qh << 32));

      if (tt + 1 < T) {
        // drain h stores + uvN loads (dep-carried so uv copy can't hoist)
        asm volatile("s_waitcnt vmcnt(0)"
                     : "+v"(uvN0), "+v"(uvN1), "+v"(uvN2), "+v"(uvN3) :: "memory");
        __syncthreads();
        u32 target = (u32)(t0 + tt + 1);
        if (tid == 0) coh_store32(flags + (size_t)nb * 32, target);
        if (wave == 0) {
          const u32* f0 = flags + (size_t)lane * 32;
          while (!__all(coh_load32(f0) >= target))
            __builtin_amdgcn_s_sleep(1);
        } else if (wave == 1) {
          u32 t2 = (u32)(t0 + (tt + 3 < T ? tt + 3 : T));
          const u32* p0 = flags + (size_t)(NWGC + 2 * lane) * 32;
          while (!__all(coh_load32(p0) >= t2 && coh_load32(p0 + 32) >= t2))
            __builtin_amdgcn_s_sleep(1);
        }
        __syncthreads();
        uv[0] = uvN0; uv[1] = uvN1; uv[2] = uvN2; uv[3] = uvN3;
      }
    }
  } else {
    // ================= PRODUCER (byte-identical to r14, proven) =================
    float* pred = (float*)smem;  // [kh2][nt8][col16][row16] f32 = 16 KiB
    int pid = blockIdx.x - NWGC;
    int btp = pid & 3;
    int n0 = (pid >> 2) * 128;
    int nt = wave & 7, kh = wave >> 3;

    const _Float16* xa = xs + (size_t)(btp * 16 + l15) * SEQL * (2 * INF)
                            + kh * 256 + lg * 8;
    const _Float16* whp = whi + (size_t)(n0 + nt * 16 + l15) * INF + kh * 256 + lg * 8;
    const _Float16* wlp = wlo + (size_t)(n0 + nt * 16 + l15) * INF + kh * 256 + lg * 8;
    float* pp = pred + (((kh * 8 + nt) * 16 + l15) * 16 + lg * 4);

    int b_l = tid >> 6, g_l = tid & 63;
    int bg = btp * 16 + b_l;
    int g0 = n0 + g_l, g1 = n0 + g_l + 64;
    size_t gi0 = (size_t)bg * GG + g0, gi1 = (size_t)bg * GG + g1;
    float vr0 = vst[gi0], vr1 = vst[gi1];
    float mr0 = mst[gi0], mr1 = mst[gi1];
    float bi0 = bih[g0], bi1 = bih[g1];
    int nt0 = g_l >> 4, c0i = g_l & 15;
    int nt1 = (g_l + 64) >> 4, c1i = g_l & 15;
    __syncthreads();

    for (int tt = 0; tt < T; ++tt) {
      const _Float16* xt = xa + (size_t)(t0 + tt) * (2 * INF);
      f32x4 aM = {}, aL = {};
#pragma unroll
      for (int kk = 0; kk < 256; kk += 32) {
        half8 ah = *(const half8*)(xt + kk);
        half8 al = *(const half8*)(xt + INF + kk);
        half8 bh = *(const half8*)(whp + kk);
        half8 bl = *(const half8*)(wlp + kk);
        aM = mfma16(ah, bh, aM);
        aL = mfma16(al, bh, aL);
        aL = mfma16(ah, bl, aL);
      }
      f32x4 cb;
#pragma unroll
      for (int i2 = 0; i2 < 4; ++i2) cb[i2] = aM[i2] + aL[i2] * ISCL;
      *(f32x4*)pp = cb;
      __syncthreads();

      float rec0 = pred[((0 + nt0) * 16 + c0i) * 16 + b_l] +
                   pred[((8 + nt0) * 16 + c0i) * 16 + b_l];
      float rec1 = pred[((0 + nt1) * 16 + c1i) * 16 + b_l] +
                   pred[((8 + nt1) * 16 + c1i) * 16 + b_l];
      float gr0 = rec0 + bi0, gr1 = rec1 + bi1;
      vr0 = MU_ * vr0 + SSTEP_ * gr0;
      mr0 = BETA_ * mr0 + (1.0f - BETA_) * gr0 * gr0;
      vr1 = MU_ * vr1 + SSTEP_ * gr1;
      mr1 = BETA_ * mr1 + (1.0f - BETA_) * gr1 * gr1;
      float* ub = u + ((size_t)tt * BB + bg) * GG;
      coh_storef(ub + g0, vr0 / (sqrtf(mr0) + EPS_));
      coh_storef(ub + g1, vr1 / (sqrtf(mr1) + EPS_));
      if (tt == T - 1) {
        vst[gi0] = vr0; vst[gi1] = vr1;
        mst[gi0] = mr0; mst[gi1] = mr1;
      }
      asm volatile("s_waitcnt vmcnt(0)" ::: "memory");  // u stores drained
      __syncthreads();
      if (tid == 0)
        coh_store32(flags + (size_t)(NWGC + pid) * 32, (u32)(t0 + tt + 1));
    }
  }
}

extern "C" void kernel_launch(void* const* d_in, const int* in_sizes, int n_in,
                              void* d_out, int out_size, void* d_ws, size_t ws_size,
                              hipStream_t stream) {
  const float* x   = (const float*)d_in[0];
  const float* wih = (const float*)d_in[1];
  const float* whh = (const float*)d_in[2];
  const float* bih = (const float*)d_in[3];
  const float* bhh = (const float*)d_in[4];
  const float* h0  = (const float*)d_in[5];
  const float* c0  = (const float*)d_in[6];
  const float* v0  = (const float*)d_in[7];
  const float* m0  = (const float*)d_in[8];

  float* out  = (float*)d_out;
  float* lout = out;
  float* hout = out + (size_t)BB * SEQL * HID;
  float* cout = hout + (size_t)BB * HID;   // running c
  float* vout = cout + (size_t)BB * HID;   // running v
  float* mout = vout + (size_t)BB * GG;    // running m

  char* ws = (char*)d_ws;
  size_t o = 0;
  _Float16* wih_hi = (_Float16*)(ws + o); o += (size_t)GG * INF * 2;
  _Float16* wih_lo = (_Float16*)(ws + o); o += (size_t)GG * INF * 2;
  _Float16* whh_hi = (_Float16*)(ws + o); o += (size_t)GG * HID * 2;
  _Float16* whh_lo = (_Float16*)(ws + o); o += (size_t)GG * HID * 2;  // staging only
  _Float16* xs     = (_Float16*)(ws + o); o += (size_t)BB * SEQL * 2 * INF * 2;  // 64 MiB
  _Float16* hA     = (_Float16*)(ws + o); o += (size_t)BB * HID * 2;
  _Float16* hB     = (_Float16*)(ws + o); o += (size_t)BB * HID * 2;
  o = (o + 255) & ~(size_t)255;
  u32* flags = (u32*)(ws + o); o += (size_t)NWG_TOT * 32 * 4;
  float* U = (float*)(ws + o);

  const size_t STEP_BYTES = (size_t)BB * GG * sizeof(float);
  size_t cap = (ws_size > o) ? (ws_size - o) / STEP_BYTES : 1;
  if (cap < 1) cap = 1;
  int Tc = (int)(cap < (size_t)SEQL ? cap : (size_t)SEQL);

  split_x<<<(BB * SEQL * INF / 8) / 256, 256, 0, stream>>>(x, xs);
  transpose_split<<<dim3(GG / 32, INF / 32), 256, 0, stream>>>(wih, wih_hi, wih_lo, INF, GG);
  transpose_split<<<dim3(GG / 32, HID / 32), 256, 0, stream>>>(whh, whh_hi, whh_lo, HID, GG);
  init_state<<<(BB * GG) / 256, 256, 0, stream>>>(h0, c0, v0, m0, cout, vout, mout, hA);
  hipMemsetAsync(flags, 0, (size_t)NWG_TOT * 32 * 4, stream);

  for (int t0 = 0; t0 < SEQL; t0 += Tc) {
    int T = (SEQL - t0 < Tc) ? (SEQL - t0) : Tc;
    rnn_fused<<<NWG_TOT, NTHR, SMEM_BYTES, stream>>>(
        xs, wih_hi, wih_lo, bih, U, whh_hi, bhh,
        hA, hB, lout, hout, cout, vout, mout, flags, t0, T);
  }
}

// Round 17
// 4579.869 us; speedup vs baseline: 1.3360x; 1.0011x over previous
//
#include <hip/hip_runtime.h>
#include <cstdint>
#include <cstddef>

#define BB   64
#define SEQL 512
#define INF  512
#define HID  1024
#define GG   4096   // 4*HID

#define MU_    0.9f
#define SSTEP_ 0.1f
#define BETA_  0.999f
#define EPS_   1e-16f
#define SCL    2048.0f
#define ISCL   (1.0f / 2048.0f)

#define NWGC  64                         // consumer wgs (recurrence)
#define NWGP  128                        // producer wgs (grad GEMM + vm scan)
#define NWG_TOT (NWGC + NWGP)
#define NTHR  1024
#define WLDS  131072                     // W_hh f16 single-plane, frag order
#define RLDS  32768                      // reduce slots
#define SMEM_BYTES (WLDS + RLDS)         // 163840 = 160 KiB exactly

typedef unsigned short u16;
typedef unsigned int   u32;
typedef unsigned long long u64;
typedef _Float16 half8 __attribute__((ext_vector_type(8)));
typedef float f32x4 __attribute__((ext_vector_type(4)));
typedef u32 u32x4 __attribute__((ext_vector_type(4)));

__device__ __forceinline__ f32x4 mfma16(half8 a, half8 b, f32x4 c) {
  return __builtin_amdgcn_mfma_f32_16x16x32_f16(a, b, c, 0, 0, 0);
}
__device__ __forceinline__ void fsplit(float v, _Float16& hi, _Float16& lo) {
  hi = (_Float16)v;
  lo = (_Float16)((v - (float)hi) * SCL);
}
// fast transcendentals: v_exp_f32 + v_rcp_f32 (rel err ~1e-6; saturation exact)
__device__ __forceinline__ float frcp(float x) { return __builtin_amdgcn_rcpf(x); }
__device__ __forceinline__ float fsig(float x) { return frcp(1.0f + __expf(-x)); }
__device__ __forceinline__ float ftanh(float x) {
  return 1.0f - 2.0f * frcp(__expf(2.0f * x) + 1.0f);
}
// device-coherent (cross-XCD) atomic ops (proven path)
__device__ __forceinline__ u32 coh_load32(const u32* p) {
  return __hip_atomic_load(p, __ATOMIC_RELAXED, __HIP_MEMORY_SCOPE_AGENT);
}
__device__ __forceinline__ void coh_store32(u32* p, u32 v) {
  __hip_atomic_store(p, v, __ATOMIC_RELAXED, __HIP_MEMORY_SCOPE_AGENT);
}
__device__ __forceinline__ void coh_store64(u64* p, u64 v) {
  __hip_atomic_store(p, v, __ATOMIC_RELAXED, __HIP_MEMORY_SCOPE_AGENT);
}
__device__ __forceinline__ void coh_storef(float* p, float v) {
  __hip_atomic_store(p, v, __ATOMIC_RELAXED, __HIP_MEMORY_SCOPE_AGENT);
}

// 8 batched device-coherent 16B loads from base addr (+ kk*64B), one asm block.
#define GLD8(o0,o1,o2,o3,o4,o5,o6,o7,addr)                      \
  asm volatile(                                                 \
    "global_load_dwordx4 %0, %8, off sc0 sc1\n\t"               \
    "global_load_dwordx4 %1, %8, off offset:64 sc0 sc1\n\t"     \
    "global_load_dwordx4 %2, %8, off offset:128 sc0 sc1\n\t"    \
    "global_load_dwordx4 %3, %8, off offset:192 sc0 sc1\n\t"    \
    "global_load_dwordx4 %4, %8, off offset:256 sc0 sc1\n\t"    \
    "global_load_dwordx4 %5, %8, off offset:320 sc0 sc1\n\t"    \
    "global_load_dwordx4 %6, %8, off offset:384 sc0 sc1\n\t"    \
    "global_load_dwordx4 %7, %8, off offset:448 sc0 sc1"        \
    : "=&v"(o0), "=&v"(o1), "=&v"(o2), "=&v"(o3),               \
      "=&v"(o4), "=&v"(o5), "=&v"(o6), "=&v"(o7)                \
    : "v"(addr))

// 4 batched coherent dword loads (u prefetch), one asm block.
#define GLDU4(d0,d1,d2,d3,a0,a1,a2,a3)                          \
  asm volatile(                                                 \
    "global_load_dword %0, %4, off sc0 sc1\n\t"                 \
    "global_load_dword %1, %5, off sc0 sc1\n\t"                 \
    "global_load_dword %2, %6, off sc0 sc1\n\t"                 \
    "global_load_dword %3, %7, off sc0 sc1"                     \
    : "=&v"(d0), "=&v"(d1), "=&v"(d2), "=&v"(d3)                \
    : "v"(a0), "v"(a1), "v"(a2), "v"(a3))

// MFMA cluster for one kk: h fragment x 4 rt weight tiles (gates 0..3).
#define HIMF(Hk, kk)                                                        \
  {                                                                         \
    half8 ah = __builtin_bit_cast(half8, Hk);                               \
    const _Float16* wb = Wf + (size_t)((kq * 8 + (kk)) * 4) * 512 + lane * 8;\
    a0 = mfma16(ah, *(const half8*)(wb), a0);                               \
    a1 = mfma16(ah, *(const half8*)(wb + 512), a1);                         \
    a2 = mfma16(ah, *(const half8*)(wb + 1024), a2);                        \
    a3 = mfma16(ah, *(const half8*)(wb + 1536), a3);                        \
  }

// ---- transpose + f16-split: src [R][C] f32 -> dhi/dlo [C][R] f16 ----
__global__ __launch_bounds__(256) void transpose_split(const float* __restrict__ src,
                                                       _Float16* __restrict__ dhi,
                                                       _Float16* __restrict__ dlo,
                                                       int R, int C) {
  __shared__ float tile[32][33];
  int c0 = blockIdx.x * 32, r0 = blockIdx.y * 32;
  int tx = threadIdx.x & 31, ty = threadIdx.x >> 5;
#pragma unroll
  for (int i = 0; i < 32; i += 8)
    tile[ty + i][tx] = src[(size_t)(r0 + ty + i) * C + (c0 + tx)];
  __syncthreads();
#pragma unroll
  for (int i = 0; i < 32; i += 8) {
    float v = tile[tx][ty + i];
    _Float16 hi, lo;
    fsplit(v, hi, lo);
    size_t o = (size_t)(c0 + ty + i) * R + (r0 + tx);
    dhi[o] = hi;
    dlo[o] = lo;
  }
}

// ---- pre-split x: f32 [B*S][IN] -> f16 [B*S][2][IN] (hi plane, lo plane) ----
__global__ __launch_bounds__(256) void split_x(const float* __restrict__ x,
                                               _Float16* __restrict__ xs) {
  size_t i = (size_t)blockIdx.x * 256 + threadIdx.x;   // one 8-elem chunk
  size_t e = i * 8;
  size_t r = e / INF, col = e % INF;
  f32x4 v0 = *(const f32x4*)(x + e);
  f32x4 v1 = *(const f32x4*)(x + e + 4);
  half8 hi, lo;
#pragma unroll
  for (int j = 0; j < 4; j++) {
    _Float16 h_, l_;
    fsplit(v0[j], h_, l_); hi[j] = h_; lo[j] = l_;
    fsplit(v1[j], h_, l_); hi[4 + j] = h_; lo[4 + j] = l_;
  }
  _Float16* dst = xs + r * 2 * INF + col;
  *(half8*)(dst) = hi;
  *(half8*)(dst + INF) = lo;
}

// ---- init running state (h -> single f16 plane) ----
__global__ __launch_bounds__(256) void init_state(const float* __restrict__ h0,
                                                  const float* __restrict__ c0,
                                                  const float* __restrict__ v0,
                                                  const float* __restrict__ m0,
                                                  float* __restrict__ co,
                                                  float* __restrict__ vo,
                                                  float* __restrict__ mo,
                                                  _Float16* __restrict__ hhi) {
  int i = blockIdx.x * 256 + threadIdx.x;
  if (i < BB * GG) { vo[i] = v0[i]; mo[i] = m0[i]; }
  if (i < BB * HID) {
    co[i] = c0[i];
    hhi[i] = (_Float16)h0[i];
  }
}

// ---- FUSED persistent kernel: 192 wgs x 1024 thr (r16 structure) ----
// Changes vs r16: (1) fast sigmoid/tanh via v_exp+v_rcp (~150 fewer VALU
// insts/thread in the serial epilogue chain); (2) lout store moved after the
// flag store so its ack hides under the poll instead of the pre-flag drain.
__global__ __attribute__((amdgpu_flat_work_group_size(NTHR, NTHR),
                          amdgpu_waves_per_eu(4, 4))) void rnn_fused(
    const _Float16* __restrict__ xs,      // [B*S][2][IN]
    const _Float16* __restrict__ whi,     // W_ih^T hi [G][IN]
    const _Float16* __restrict__ wlo,     // W_ih^T lo [G][IN]
    const float* __restrict__ bih,
    float* __restrict__ u,                // [T][B][G] produced in-kernel
    const _Float16* __restrict__ whh_hi,  // [G][H] f16
    const float* __restrict__ bhh,
    _Float16* __restrict__ hA, _Float16* __restrict__ hB,
    float* __restrict__ lout, float* __restrict__ hout,
    float* __restrict__ cout,             // running c
    float* __restrict__ vst, float* __restrict__ mst,  // running v,m
    u32* __restrict__ flags, int t0, int T) {
  extern __shared__ char smem[];
  int tid = threadIdx.x;
  int wave = tid >> 6, lane = tid & 63;
  int l15 = lane & 15, lg = lane >> 4;

  if (blockIdx.x < NWGC) {
    // ================= CONSUMER =================
    _Float16* Wf = (_Float16*)smem;               // 128 KiB frag-order weights
    float* red = (float*)(smem + WLDS);           // [bt4][kqh2][rt4][col16][16]
    int bt = wave >> 2, kq = wave & 3;
    int nb = blockIdx.x;

    // stage W_hh slice into LDS in fragment order
    for (int s = tid; s < 8192; s += NTHR) {
      int ln = s & 63, rest = s >> 6;
      int rt = rest & 3, kk = (rest >> 2) & 7, kq2 = rest >> 5;
      int grow = rt * HID + nb * 16 + (ln & 15);
      int k = kq2 * 256 + kk * 32 + (ln >> 4) * 8;
      *(half8*)(Wf + (size_t)s * 8) = *(const half8*)(whh_hi + (size_t)grow * HID + k);
    }

    // epilogue constants: thread = (batch bo, cell j)
    int bo = tid >> 4, j = tid & 15;
    int en = nb * 16 + j;
    int within = bo & 15, btE = bo >> 4;
    int wsl = (((within >> 2) + j) & 3) * 4 + (within & 3);  // de-swizzle slot
    float bh_[4], creg;
#pragma unroll
    for (int q = 0; q < 4; q++) bh_[q] = bhh[q * HID + en];
    creg = cout[(size_t)bo * HID + en];
    // h fragment byte offset for this lane's GEMM A-row
    u64 hOffB = (u64)(((bt * 16 + l15) * HID + kq * 256 + lg * 8) * 2);
    u64 hAB = (u64)(uintptr_t)hA + hOffB;
    u64 hBB = (u64)(uintptr_t)hB + hOffB;
    // shfl-pack h store targets: thread (bo, j), j%4==0 stores u64 of 4 cells
    u64* wSA = (u64*)(hA + (size_t)bo * HID + nb * 16) + (j >> 2);
    u64* wSB = (u64*)(hB + (size_t)bo * HID + nb * 16) + (j >> 2);
    // per-thread u base address (q=0 gate)
    u64 ubT = (u64)(uintptr_t)u + (((size_t)bo * GG) + en) * 4;
    __syncthreads();

    // wait for producers: u[t0] and u[t0+1]
    if (wave == 0) {
      u32 tp = (u32)(t0 + (T < 2 ? T : 2));
      const u32* p0 = flags + (size_t)(NWGC + 2 * lane) * 32;
      while (!__all(coh_load32(p0) >= tp && coh_load32(p0 + 32) >= tp))
        __builtin_amdgcn_s_sleep(1);
    }
    __syncthreads();
    float uvA, uvB, uvC, uvD;
    GLDU4(uvA, uvB, uvC, uvD, ubT, ubT + 4096, ubT + 8192, ubT + 12288);
    asm volatile("s_waitcnt vmcnt(0)"
                 : "+v"(uvA), "+v"(uvB), "+v"(uvC), "+v"(uvD) :: "memory");
    float uv[4] = {uvA, uvB, uvC, uvD};

    for (int tt = 0; tt < T; ++tt) {
      int gt = t0 + tt;
      u64 rB = (gt & 1) ? hBB : hAB;

      u32x4 H0, H1, H2, H3, H4, H5, H6, H7;
      GLD8(H0, H1, H2, H3, H4, H5, H6, H7, rB);
      asm volatile("s_waitcnt vmcnt(0)" ::: "memory");   // h landed
      __builtin_amdgcn_sched_barrier(0);

      f32x4 a0 = {}, a1 = {}, a2 = {}, a3 = {};
      HIMF(H0, 0) HIMF(H1, 1) HIMF(H2, 2) HIMF(H3, 3)
      HIMF(H4, 4) HIMF(H5, 5) HIMF(H6, 6) HIMF(H7, 7)

      // pairwise kq reduce in LDS, granule-rotation swizzled
      int kqh = kq >> 1;
      int p = (lg + l15) & 3;
      int sB0 = (((bt * 2 + kqh) * 4 + 0) * 16 + l15) * 16 + p * 4;
      int sB1 = (((bt * 2 + kqh) * 4 + 1) * 16 + l15) * 16 + p * 4;
      int sB2 = (((bt * 2 + kqh) * 4 + 2) * 16 + l15) * 16 + p * 4;
      int sB3 = (((bt * 2 + kqh) * 4 + 3) * 16 + l15) * 16 + p * 4;
      if (kq & 1) {
        *(f32x4*)(red + sB0) = a0;
        *(f32x4*)(red + sB1) = a1;
        *(f32x4*)(red + sB2) = a2;
        *(f32x4*)(red + sB3) = a3;
      }
      __syncthreads();
      if (!(kq & 1)) {
        *(f32x4*)(red + sB0) = a0 + *(const f32x4*)(red + sB0);
        *(f32x4*)(red + sB1) = a1 + *(const f32x4*)(red + sB1);
        *(f32x4*)(red + sB2) = a2 + *(const f32x4*)(red + sB2);
        *(f32x4*)(red + sB3) = a3 + *(const f32x4*)(red + sB3);
      }
      // coherent prefetch of next step's u
      float uvN0 = 0, uvN1 = 0, uvN2 = 0, uvN3 = 0;
      if (tt + 1 < T) {
        u64 ubn = ubT + ((u64)(tt + 1) * ((u64)BB * GG * 4));
        GLDU4(uvN0, uvN1, uvN2, uvN3, ubn, ubn + 4096, ubn + 8192, ubn + 12288);
      }
      __syncthreads();

      // epilogue: all 1024 threads; fast transcendentals
      float gate[4];
#pragma unroll
      for (int q = 0; q < 4; q++) {
        float rec = red[(((btE * 2 + 0) * 4 + q) * 16 + j) * 16 + wsl] +
                    red[(((btE * 2 + 1) * 4 + q) * 16 + j) * 16 + wsl];
        gate[q] = uv[q] + rec + bh_[q];
      }
      float ig = fsig(gate[0]);
      float fg = fsig(gate[1]);
      float gg = ftanh(gate[2]);
      float og = fsig(gate[3]);
      creg = creg * fg + ig * gg;
      float hh = og * ftanh(creg);

      if (gt == SEQL - 1) hout[(size_t)bo * HID + en] = hh;
      if (tt == T - 1)    cout[(size_t)bo * HID + en] = creg;

      // shfl-pack h -> 256 coherent u64 stores
      u32 myh = (u32)__builtin_bit_cast(u16, (_Float16)hh);
      u32 oh = __shfl_xor(myh, 1);
      u32 ph = (j & 1) ? (oh | (myh << 16)) : (myh | (oh << 16));
      u32 qh = __shfl_xor(ph, 2);
      if ((j & 3) == 0)
        coh_store64((gt & 1) ? wSA : wSB, (u64)ph | ((u64)qh << 32));

      if (tt + 1 < T) {
        // drain h stores + uvN loads (dep-carried so uv copy can't hoist)
        asm volatile("s_waitcnt vmcnt(0)"
                     : "+v"(uvN0), "+v"(uvN1), "+v"(uvN2), "+v"(uvN3) :: "memory");
        __syncthreads();
        u32 target = (u32)(t0 + tt + 1);
        if (tid == 0) coh_store32(flags + (size_t)nb * 32, target);
        // lout store issued here: its write-ack hides under the flag poll
        lout[((size_t)bo * SEQL + gt) * HID + en] = hh;
        if (wave == 0) {
          const u32* f0 = flags + (size_t)lane * 32;
          while (!__all(coh_load32(f0) >= target))
            __builtin_amdgcn_s_sleep(1);
        } else if (wave == 1) {
          u32 t2 = (u32)(t0 + (tt + 3 < T ? tt + 3 : T));
          const u32* p0 = flags + (size_t)(NWGC + 2 * lane) * 32;
          while (!__all(coh_load32(p0) >= t2 && coh_load32(p0 + 32) >= t2))
            __builtin_amdgcn_s_sleep(1);
        }
        __syncthreads();
        uv[0] = uvN0; uv[1] = uvN1; uv[2] = uvN2; uv[3] = uvN3;
      } else {
        lout[((size_t)bo * SEQL + gt) * HID + en] = hh;
      }
    }
  } else {
    // ================= PRODUCER (byte-identical to r14/r16, proven) =========
    float* pred = (float*)smem;  // [kh2][nt8][col16][row16] f32 = 16 KiB
    int pid = blockIdx.x - NWGC;
    int btp = pid & 3;
    int n0 = (pid >> 2) * 128;
    int nt = wave & 7, kh = wave >> 3;

    const _Float16* xa = xs + (size_t)(btp * 16 + l15) * SEQL * (2 * INF)
                            + kh * 256 + lg * 8;
    const _Float16* whp = whi + (size_t)(n0 + nt * 16 + l15) * INF + kh * 256 + lg * 8;
    const _Float16* wlp = wlo + (size_t)(n0 + nt * 16 + l15) * INF + kh * 256 + lg * 8;
    float* pp = pred + (((kh * 8 + nt) * 16 + l15) * 16 + lg * 4);

    int b_l = tid >> 6, g_l = tid & 63;
    int bg = btp * 16 + b_l;
    int g0 = n0 + g_l, g1 = n0 + g_l + 64;
    size_t gi0 = (size_t)bg * GG + g0, gi1 = (size_t)bg * GG + g1;
    float vr0 = vst[gi0], vr1 = vst[gi1];
    float mr0 = mst[gi0], mr1 = mst[gi1];
    float bi0 = bih[g0], bi1 = bih[g1];
    int nt0 = g_l >> 4, c0i = g_l & 15;
    int nt1 = (g_l + 64) >> 4, c1i = g_l & 15;
    __syncthreads();

    for (int tt = 0; tt < T; ++tt) {
      const _Float16* xt = xa + (size_t)(t0 + tt) * (2 * INF);
      f32x4 aM = {}, aL = {};
#pragma unroll
      for (int kk = 0; kk < 256; kk += 32) {
        half8 ah = *(const half8*)(xt + kk);
        half8 al = *(const half8*)(xt + INF + kk);
        half8 bh = *(const half8*)(whp + kk);
        half8 bl = *(const half8*)(wlp + kk);
        aM = mfma16(ah, bh, aM);
        aL = mfma16(al, bh, aL);
        aL = mfma16(ah, bl, aL);
      }
      f32x4 cb;
#pragma unroll
      for (int i2 = 0; i2 < 4; ++i2) cb[i2] = aM[i2] + aL[i2] * ISCL;
      *(f32x4*)pp = cb;
      __syncthreads();

      float rec0 = pred[((0 + nt0) * 16 + c0i) * 16 + b_l] +
                   pred[((8 + nt0) * 16 + c0i) * 16 + b_l];
      float rec1 = pred[((0 + nt1) * 16 + c1i) * 16 + b_l] +
                   pred[((8 + nt1) * 16 + c1i) * 16 + b_l];
      float gr0 = rec0 + bi0, gr1 = rec1 + bi1;
      vr0 = MU_ * vr0 + SSTEP_ * gr0;
      mr0 = BETA_ * mr0 + (1.0f - BETA_) * gr0 * gr0;
      vr1 = MU_ * vr1 + SSTEP_ * gr1;
      mr1 = BETA_ * mr1 + (1.0f - BETA_) * gr1 * gr1;
      float* ub = u + ((size_t)tt * BB + bg) * GG;
      coh_storef(ub + g0, vr0 / (sqrtf(mr0) + EPS_));
      coh_storef(ub + g1, vr1 / (sqrtf(mr1) + EPS_));
      if (tt == T - 1) {
        vst[gi0] = vr0; vst[gi1] = vr1;
        mst[gi0] = mr0; mst[gi1] = mr1;
      }
      asm volatile("s_waitcnt vmcnt(0)" ::: "memory");  // u stores drained
      __syncthreads();
      if (tid == 0)
        coh_store32(flags + (size_t)(NWGC + pid) * 32, (u32)(t0 + tt + 1));
    }
  }
}

extern "C" void kernel_launch(void* const* d_in, const int* in_sizes, int n_in,
                              void* d_out, int out_size, void* d_ws, size_t ws_size,
                              hipStream_t stream) {
  const float* x   = (const float*)d_in[0];
  const float* wih = (const float*)d_in[1];
  const float* whh = (const float*)d_in[2];
  const float* bih = (const float*)d_in[3];
  const float* bhh = (const float*)d_in[4];
  const float* h0  = (const float*)d_in[5];
  const float* c0  = (const float*)d_in[6];
  const float* v0  = (const float*)d_in[7];
  const float* m0  = (const float*)d_in[8];

  float* out  = (float*)d_out;
  float* lout = out;
  float* hout = out + (size_t)BB * SEQL * HID;
  float* cout = hout + (size_t)BB * HID;   // running c
  float* vout = cout + (size_t)BB * HID;   // running v
  float* mout = vout + (size_t)BB * GG;    // running m

  char* ws = (char*)d_ws;
  size_t o = 0;
  _Float16* wih_hi = (_Float16*)(ws + o); o += (size_t)GG * INF * 2;
  _Float16* wih_lo = (_Float16*)(ws + o); o += (size_t)GG * INF * 2;
  _Float16* whh_hi = (_Float16*)(ws + o); o += (size_t)GG * HID * 2;
  _Float16* whh_lo = (_Float16*)(ws + o); o += (size_t)GG * HID * 2;  // staging only
  _Float16* xs     = (_Float16*)(ws + o); o += (size_t)BB * SEQL * 2 * INF * 2;  // 64 MiB
  _Float16* hA     = (_Float16*)(ws + o); o += (size_t)BB * HID * 2;
  _Float16* hB     = (_Float16*)(ws + o); o += (size_t)BB * HID * 2;
  o = (o + 255) & ~(size_t)255;
  u32* flags = (u32*)(ws + o); o += (size_t)NWG_TOT * 32 * 4;
  float* U = (float*)(ws + o);

  const size_t STEP_BYTES = (size_t)BB * GG * sizeof(float);
  size_t cap = (ws_size > o) ? (ws_size - o) / STEP_BYTES : 1;
  if (cap < 1) cap = 1;
  int Tc = (int)(cap < (size_t)SEQL ? cap : (size_t)SEQL);

  split_x<<<(BB * SEQL * INF / 8) / 256, 256, 0, stream>>>(x, xs);
  transpose_split<<<dim3(GG / 32, INF / 32), 256, 0, stream>>>(wih, wih_hi, wih_lo, INF, GG);
  transpose_split<<<dim3(GG / 32, HID / 32), 256, 0, stream>>>(whh, whh_hi, whh_lo, HID, GG);
  init_state<<<(BB * GG) / 256, 256, 0, stream>>>(h0, c0, v0, m0, cout, vout, mout, hA);
  hipMemsetAsync(flags, 0, (size_t)NWG_TOT * 32 * 4, stream);

  for (int t0 = 0; t0 < SEQL; t0 += Tc) {
    int T = (SEQL - t0 < Tc) ? (SEQL - t0) : Tc;
    rnn_fused<<<NWG_TOT, NTHR, SMEM_BYTES, stream>>>(
        xs, wih_hi, wih_lo, bih, U, whh_hi, bhh,
        hA, hB, lout, hout, cout, vout, mout, flags, t0, T);
  }
}

// Round 18
// 4315.698 us; speedup vs baseline: 1.4177x; 1.0612x over previous
//
#include <hip/hip_runtime.h>
#include <cstdint>
#include <cstddef>

#define BB   64
#define SEQL 512
#define INF  512
#define HID  1024
#define GG   4096   // 4*HID

#define MU_    0.9f
#define SSTEP_ 0.1f
#define BETA_  0.999f
#define EPS_   1e-16f
#define SCL    2048.0f
#define ISCL   (1.0f / 2048.0f)

#define NWGC  64                         // consumer wgs (recurrence)
#define NWGP  128                        // producer wgs (grad GEMM + vm scan)
#define NWG_TOT (NWGC + NWGP)
#define NTHR  1024
#define WLDS  131072                     // W_hh f16 single-plane, frag order
#define RLDS  32768                      // reduce slots
#define SMEM_BYTES (WLDS + RLDS)         // 163840 = 160 KiB exactly

typedef unsigned short u16;
typedef unsigned int   u32;
typedef unsigned long long u64;
typedef _Float16 half8 __attribute__((ext_vector_type(8)));
typedef float f32x4 __attribute__((ext_vector_type(4)));
typedef u32 u32x4 __attribute__((ext_vector_type(4)));

__device__ __forceinline__ f32x4 mfma16(half8 a, half8 b, f32x4 c) {
  return __builtin_amdgcn_mfma_f32_16x16x32_f16(a, b, c, 0, 0, 0);
}
__device__ __forceinline__ void fsplit(float v, _Float16& hi, _Float16& lo) {
  hi = (_Float16)v;
  lo = (_Float16)((v - (float)hi) * SCL);
}
// fast transcendentals: v_exp_f32 + v_rcp_f32 (rel err ~1e-6; saturation exact)
__device__ __forceinline__ float frcp(float x) { return __builtin_amdgcn_rcpf(x); }
__device__ __forceinline__ float fsig(float x) { return frcp(1.0f + __expf(-x)); }
__device__ __forceinline__ float ftanh(float x) {
  return 1.0f - 2.0f * frcp(__expf(2.0f * x) + 1.0f);
}
// device-coherent (cross-XCD) atomic ops (proven path)
__device__ __forceinline__ u32 coh_load32(const u32* p) {
  return __hip_atomic_load(p, __ATOMIC_RELAXED, __HIP_MEMORY_SCOPE_AGENT);
}
__device__ __forceinline__ void coh_store32(u32* p, u32 v) {
  __hip_atomic_store(p, v, __ATOMIC_RELAXED, __HIP_MEMORY_SCOPE_AGENT);
}
__device__ __forceinline__ void coh_store64(u64* p, u64 v) {
  __hip_atomic_store(p, v, __ATOMIC_RELAXED, __HIP_MEMORY_SCOPE_AGENT);
}
__device__ __forceinline__ void coh_storef(float* p, float v) {
  __hip_atomic_store(p, v, __ATOMIC_RELAXED, __HIP_MEMORY_SCOPE_AGENT);
}

// 8 batched device-coherent 16B loads from base addr (+ kk*64B), one asm block.
#define GLD8(o0,o1,o2,o3,o4,o5,o6,o7,addr)                      \
  asm volatile(                                                 \
    "global_load_dwordx4 %0, %8, off sc0 sc1\n\t"               \
    "global_load_dwordx4 %1, %8, off offset:64 sc0 sc1\n\t"     \
    "global_load_dwordx4 %2, %8, off offset:128 sc0 sc1\n\t"    \
    "global_load_dwordx4 %3, %8, off offset:192 sc0 sc1\n\t"    \
    "global_load_dwordx4 %4, %8, off offset:256 sc0 sc1\n\t"    \
    "global_load_dwordx4 %5, %8, off offset:320 sc0 sc1\n\t"    \
    "global_load_dwordx4 %6, %8, off offset:384 sc0 sc1\n\t"    \
    "global_load_dwordx4 %7, %8, off offset:448 sc0 sc1"        \
    : "=&v"(o0), "=&v"(o1), "=&v"(o2), "=&v"(o3),               \
      "=&v"(o4), "=&v"(o5), "=&v"(o6), "=&v"(o7)                \
    : "v"(addr))

// 4 batched coherent dword loads (u prefetch), one asm block.
#define GLDU4(d0,d1,d2,d3,a0,a1,a2,a3)                          \
  asm volatile(                                                 \
    "global_load_dword %0, %4, off sc0 sc1\n\t"                 \
    "global_load_dword %1, %5, off sc0 sc1\n\t"                 \
    "global_load_dword %2, %6, off sc0 sc1\n\t"                 \
    "global_load_dword %3, %7, off sc0 sc1"                     \
    : "=&v"(d0), "=&v"(d1), "=&v"(d2), "=&v"(d3)                \
    : "v"(a0), "v"(a1), "v"(a2), "v"(a3))

// MFMA cluster for one kk: h fragment x 4 rt weight tiles (gates 0..3).
#define HIMF(Hk, kk)                                                        \
  {                                                                         \
    half8 ah = __builtin_bit_cast(half8, Hk);                               \
    const _Float16* wb = Wf + (size_t)((kq * 8 + (kk)) * 4) * 512 + lane * 8;\
    a0 = mfma16(ah, *(const half8*)(wb), a0);                               \
    a1 = mfma16(ah, *(const half8*)(wb + 512), a1);                         \
    a2 = mfma16(ah, *(const half8*)(wb + 1024), a2);                        \
    a3 = mfma16(ah, *(const half8*)(wb + 1536), a3);                        \
  }

// ---- transpose + f16-split: src [R][C] f32 -> dhi/dlo [C][R] f16 ----
__global__ __launch_bounds__(256) void transpose_split(const float* __restrict__ src,
                                                       _Float16* __restrict__ dhi,
                                                       _Float16* __restrict__ dlo,
                                                       int R, int C) {
  __shared__ float tile[32][33];
  int c0 = blockIdx.x * 32, r0 = blockIdx.y * 32;
  int tx = threadIdx.x & 31, ty = threadIdx.x >> 5;
#pragma unroll
  for (int i = 0; i < 32; i += 8)
    tile[ty + i][tx] = src[(size_t)(r0 + ty + i) * C + (c0 + tx)];
  __syncthreads();
#pragma unroll
  for (int i = 0; i < 32; i += 8) {
    float v = tile[tx][ty + i];
    _Float16 hi, lo;
    fsplit(v, hi, lo);
    size_t o = (size_t)(c0 + ty + i) * R + (r0 + tx);
    dhi[o] = hi;
    dlo[o] = lo;
  }
}

// ---- pre-split x: f32 [B*S][IN] -> f16 [B*S][2][IN] (hi plane, lo plane) ----
__global__ __launch_bounds__(256) void split_x(const float* __restrict__ x,
                                               _Float16* __restrict__ xs) {
  size_t i = (size_t)blockIdx.x * 256 + threadIdx.x;   // one 8-elem chunk
  size_t e = i * 8;
  size_t r = e / INF, col = e % INF;
  f32x4 v0 = *(const f32x4*)(x + e);
  f32x4 v1 = *(const f32x4*)(x + e + 4);
  half8 hi, lo;
#pragma unroll
  for (int j = 0; j < 4; j++) {
    _Float16 h_, l_;
    fsplit(v0[j], h_, l_); hi[j] = h_; lo[j] = l_;
    fsplit(v1[j], h_, l_); hi[4 + j] = h_; lo[4 + j] = l_;
  }
  _Float16* dst = xs + r * 2 * INF + col;
  *(half8*)(dst) = hi;
  *(half8*)(dst + INF) = lo;
}

// ---- init running state (h -> single f16 plane) ----
__global__ __launch_bounds__(256) void init_state(const float* __restrict__ h0,
                                                  const float* __restrict__ c0,
                                                  const float* __restrict__ v0,
                                                  const float* __restrict__ m0,
                                                  float* __restrict__ co,
                                                  float* __restrict__ vo,
                                                  float* __restrict__ mo,
                                                  _Float16* __restrict__ hhi) {
  int i = blockIdx.x * 256 + threadIdx.x;
  if (i < BB * GG) { vo[i] = v0[i]; mo[i] = m0[i]; }
  if (i < BB * HID) {
    co[i] = c0[i];
    hhi[i] = (_Float16)h0[i];
  }
}

// ---- FUSED persistent kernel: 192 wgs x 1024 thr (r17 structure) ----
// Change vs r17: CONFLICT-FREE LDS reduce layouts (math bit-identical).
// Consumer red: row=(bt*2+kqh)*4+rt of 256 floats; writers store f32x4 at
//   lane*4 (fully linear, 0-conflict); readers at j*4+(within>>2)*64+(within&3)
//   (2 lanes/bank = free). Was 8-way on the critical path.
// Producer pred: reader-linear [kh*16+batch][128] (reads 0-conflict; writes
//   4 scalar stores at 4-way, ~wash vs old 8-way vector store).
__global__ __attribute__((amdgpu_flat_work_group_size(NTHR, NTHR),
                          amdgpu_waves_per_eu(4, 4))) void rnn_fused(
    const _Float16* __restrict__ xs,      // [B*S][2][IN]
    const _Float16* __restrict__ whi,     // W_ih^T hi [G][IN]
    const _Float16* __restrict__ wlo,     // W_ih^T lo [G][IN]
    const float* __restrict__ bih,
    float* __restrict__ u,                // [T][B][G] produced in-kernel
    const _Float16* __restrict__ whh_hi,  // [G][H] f16
    const float* __restrict__ bhh,
    _Float16* __restrict__ hA, _Float16* __restrict__ hB,
    float* __restrict__ lout, float* __restrict__ hout,
    float* __restrict__ cout,             // running c
    float* __restrict__ vst, float* __restrict__ mst,  // running v,m
    u32* __restrict__ flags, int t0, int T) {
  extern __shared__ char smem[];
  int tid = threadIdx.x;
  int wave = tid >> 6, lane = tid & 63;
  int l15 = lane & 15, lg = lane >> 4;

  if (blockIdx.x < NWGC) {
    // ================= CONSUMER =================
    _Float16* Wf = (_Float16*)smem;               // 128 KiB frag-order weights
    float* red = (float*)(smem + WLDS);           // 32 rows x 256 floats
    int bt = wave >> 2, kq = wave & 3;
    int nb = blockIdx.x;

    // stage W_hh slice into LDS in fragment order
    for (int s = tid; s < 8192; s += NTHR) {
      int ln = s & 63, rest = s >> 6;
      int rt = rest & 3, kk = (rest >> 2) & 7, kq2 = rest >> 5;
      int grow = rt * HID + nb * 16 + (ln & 15);
      int k = kq2 * 256 + kk * 32 + (ln >> 4) * 8;
      *(half8*)(Wf + (size_t)s * 8) = *(const half8*)(whh_hi + (size_t)grow * HID + k);
    }

    // epilogue constants: thread = (batch bo, cell j)
    int bo = tid >> 4, j = tid & 15;
    int en = nb * 16 + j;
    int within = bo & 15, btE = bo >> 4;
    int roff = j * 4 + (within >> 2) * 64 + (within & 3);  // linear-red read slot
    float bh_[4], creg;
#pragma unroll
    for (int q = 0; q < 4; q++) bh_[q] = bhh[q * HID + en];
    creg = cout[(size_t)bo * HID + en];
    // h fragment byte offset for this lane's GEMM A-row
    u64 hOffB = (u64)(((bt * 16 + l15) * HID + kq * 256 + lg * 8) * 2);
    u64 hAB = (u64)(uintptr_t)hA + hOffB;
    u64 hBB = (u64)(uintptr_t)hB + hOffB;
    // shfl-pack h store targets: thread (bo, j), j%4==0 stores u64 of 4 cells
    u64* wSA = (u64*)(hA + (size_t)bo * HID + nb * 16) + (j >> 2);
    u64* wSB = (u64*)(hB + (size_t)bo * HID + nb * 16) + (j >> 2);
    // per-thread u base address (q=0 gate)
    u64 ubT = (u64)(uintptr_t)u + (((size_t)bo * GG) + en) * 4;
    __syncthreads();

    // wait for producers: u[t0] and u[t0+1]
    if (wave == 0) {
      u32 tp = (u32)(t0 + (T < 2 ? T : 2));
      const u32* p0 = flags + (size_t)(NWGC + 2 * lane) * 32;
      while (!__all(coh_load32(p0) >= tp && coh_load32(p0 + 32) >= tp))
        __builtin_amdgcn_s_sleep(1);
    }
    __syncthreads();
    float uvA, uvB, uvC, uvD;
    GLDU4(uvA, uvB, uvC, uvD, ubT, ubT + 4096, ubT + 8192, ubT + 12288);
    asm volatile("s_waitcnt vmcnt(0)"
                 : "+v"(uvA), "+v"(uvB), "+v"(uvC), "+v"(uvD) :: "memory");
    float uv[4] = {uvA, uvB, uvC, uvD};

    for (int tt = 0; tt < T; ++tt) {
      int gt = t0 + tt;
      u64 rB = (gt & 1) ? hBB : hAB;

      u32x4 H0, H1, H2, H3, H4, H5, H6, H7;
      GLD8(H0, H1, H2, H3, H4, H5, H6, H7, rB);
      asm volatile("s_waitcnt vmcnt(0)" ::: "memory");   // h landed
      __builtin_amdgcn_sched_barrier(0);

      f32x4 a0 = {}, a1 = {}, a2 = {}, a3 = {};
      HIMF(H0, 0) HIMF(H1, 1) HIMF(H2, 2) HIMF(H3, 3)
      HIMF(H4, 4) HIMF(H5, 5) HIMF(H6, 6) HIMF(H7, 7)

      // pairwise kq reduce in LDS — LINEAR layout (conflict-free)
      int kqh = kq >> 1;
      int rowb = ((bt * 2 + kqh) * 4) * 256 + lane * 4;
      if (kq & 1) {
        *(f32x4*)(red + rowb) = a0;
        *(f32x4*)(red + rowb + 256) = a1;
        *(f32x4*)(red + rowb + 512) = a2;
        *(f32x4*)(red + rowb + 768) = a3;
      }
      __syncthreads();
      if (!(kq & 1)) {
        *(f32x4*)(red + rowb) = a0 + *(const f32x4*)(red + rowb);
        *(f32x4*)(red + rowb + 256) = a1 + *(const f32x4*)(red + rowb + 256);
        *(f32x4*)(red + rowb + 512) = a2 + *(const f32x4*)(red + rowb + 512);
        *(f32x4*)(red + rowb + 768) = a3 + *(const f32x4*)(red + rowb + 768);
      }
      // coherent prefetch of next step's u
      float uvN0 = 0, uvN1 = 0, uvN2 = 0, uvN3 = 0;
      if (tt + 1 < T) {
        u64 ubn = ubT + ((u64)(tt + 1) * ((u64)BB * GG * 4));
        GLDU4(uvN0, uvN1, uvN2, uvN3, ubn, ubn + 4096, ubn + 8192, ubn + 12288);
      }
      __syncthreads();

      // epilogue: all 1024 threads; fast transcendentals
      float gate[4];
#pragma unroll
      for (int q = 0; q < 4; q++) {
        float rec = red[((btE * 2 + 0) * 4 + q) * 256 + roff] +
                    red[((btE * 2 + 1) * 4 + q) * 256 + roff];
        gate[q] = uv[q] + rec + bh_[q];
      }
      float ig = fsig(gate[0]);
      float fg = fsig(gate[1]);
      float gg = ftanh(gate[2]);
      float og = fsig(gate[3]);
      creg = creg * fg + ig * gg;
      float hh = og * ftanh(creg);

      if (gt == SEQL - 1) hout[(size_t)bo * HID + en] = hh;
      if (tt == T - 1)    cout[(size_t)bo * HID + en] = creg;

      // shfl-pack h -> 256 coherent u64 stores
      u32 myh = (u32)__builtin_bit_cast(u16, (_Float16)hh);
      u32 oh = __shfl_xor(myh, 1);
      u32 ph = (j & 1) ? (oh | (myh << 16)) : (myh | (oh << 16));
      u32 qh = __shfl_xor(ph, 2);
      if ((j & 3) == 0)
        coh_store64((gt & 1) ? wSA : wSB, (u64)ph | ((u64)qh << 32));

      if (tt + 1 < T) {
        // drain h stores + uvN loads (dep-carried so uv copy can't hoist)
        asm volatile("s_waitcnt vmcnt(0)"
                     : "+v"(uvN0), "+v"(uvN1), "+v"(uvN2), "+v"(uvN3) :: "memory");
        __syncthreads();
        u32 target = (u32)(t0 + tt + 1);
        if (tid == 0) coh_store32(flags + (size_t)nb * 32, target);
        // lout store issued here: its write-ack hides under the flag poll
        lout[((size_t)bo * SEQL + gt) * HID + en] = hh;
        if (wave == 0) {
          const u32* f0 = flags + (size_t)lane * 32;
          while (!__all(coh_load32(f0) >= target))
            __builtin_amdgcn_s_sleep(1);
        } else if (wave == 1) {
          u32 t2 = (u32)(t0 + (tt + 3 < T ? tt + 3 : T));
          const u32* p0 = flags + (size_t)(NWGC + 2 * lane) * 32;
          while (!__all(coh_load32(p0) >= t2 && coh_load32(p0 + 32) >= t2))
            __builtin_amdgcn_s_sleep(1);
        }
        __syncthreads();
        uv[0] = uvN0; uv[1] = uvN1; uv[2] = uvN2; uv[3] = uvN3;
      } else {
        lout[((size_t)bo * SEQL + gt) * HID + en] = hh;
      }
    }
  } else {
    // ================= PRODUCER (r14 logic; reader-linear pred layout) ======
    float* pred = (float*)smem;  // [kh*16+batch][128 g_local] f32 = 16 KiB
    int pid = blockIdx.x - NWGC;
    int btp = pid & 3;
    int n0 = (pid >> 2) * 128;
    int nt = wave & 7, kh = wave >> 3;

    const _Float16* xa = xs + (size_t)(btp * 16 + l15) * SEQL * (2 * INF)
                            + kh * 256 + lg * 8;
    const _Float16* whp = whi + (size_t)(n0 + nt * 16 + l15) * INF + kh * 256 + lg * 8;
    const _Float16* wlp = wlo + (size_t)(n0 + nt * 16 + l15) * INF + kh * 256 + lg * 8;
    // writer slots: element i -> row kh*16 + lg*4 + i, col nt*16 + l15
    float* pp = pred + (size_t)(kh * 16 + lg * 4) * 128 + nt * 16 + l15;

    int b_l = tid >> 6, g_l = tid & 63;
    int bg = btp * 16 + b_l;
    int g0 = n0 + g_l, g1 = n0 + g_l + 64;
    size_t gi0 = (size_t)bg * GG + g0, gi1 = (size_t)bg * GG + g1;
    float vr0 = vst[gi0], vr1 = vst[gi1];
    float mr0 = mst[gi0], mr1 = mst[gi1];
    float bi0 = bih[g0], bi1 = bih[g1];
    __syncthreads();

    for (int tt = 0; tt < T; ++tt) {
      const _Float16* xt = xa + (size_t)(t0 + tt) * (2 * INF);
      f32x4 aM = {}, aL = {};
#pragma unroll
      for (int kk = 0; kk < 256; kk += 32) {
        half8 ah = *(const half8*)(xt + kk);
        half8 al = *(const half8*)(xt + INF + kk);
        half8 bh = *(const half8*)(whp + kk);
        half8 bl = *(const half8*)(wlp + kk);
        aM = mfma16(ah, bh, aM);
        aL = mfma16(al, bh, aL);
        aL = mfma16(ah, bl, aL);
      }
      // write combined partials, reader-linear layout (4 scalar stores)
      pp[0]       = aM[0] + aL[0] * ISCL;
      pp[128]     = aM[1] + aL[1] * ISCL;
      pp[256]     = aM[2] + aL[2] * ISCL;
      pp[384]     = aM[3] + aL[3] * ISCL;
      __syncthreads();

      // reads fully linear: lanes g_l consecutive floats
      float rec0 = pred[(size_t)b_l * 128 + g_l] +
                   pred[(size_t)(16 + b_l) * 128 + g_l];
      float rec1 = pred[(size_t)b_l * 128 + g_l + 64] +
                   pred[(size_t)(16 + b_l) * 128 + g_l + 64];
      float gr0 = rec0 + bi0, gr1 = rec1 + bi1;
      vr0 = MU_ * vr0 + SSTEP_ * gr0;
      mr0 = BETA_ * mr0 + (1.0f - BETA_) * gr0 * gr0;
      vr1 = MU_ * vr1 + SSTEP_ * gr1;
      mr1 = BETA_ * mr1 + (1.0f - BETA_) * gr1 * gr1;
      float* ub = u + ((size_t)tt * BB + bg) * GG;
      coh_storef(ub + g0, vr0 / (sqrtf(mr0) + EPS_));
      coh_storef(ub + g1, vr1 / (sqrtf(mr1) + EPS_));
      if (tt == T - 1) {
        vst[gi0] = vr0; vst[gi1] = vr1;
        mst[gi0] = mr0; mst[gi1] = mr1;
      }
      asm volatile("s_waitcnt vmcnt(0)" ::: "memory");  // u stores drained
      __syncthreads();
      if (tid == 0)
        coh_store32(flags + (size_t)(NWGC + pid) * 32, (u32)(t0 + tt + 1));
    }
  }
}

extern "C" void kernel_launch(void* const* d_in, const int* in_sizes, int n_in,
                              void* d_out, int out_size, void* d_ws, size_t ws_size,
                              hipStream_t stream) {
  const float* x   = (const float*)d_in[0];
  const float* wih = (const float*)d_in[1];
  const float* whh = (const float*)d_in[2];
  const float* bih = (const float*)d_in[3];
  const float* bhh = (const float*)d_in[4];
  const float* h0  = (const float*)d_in[5];
  const float* c0  = (const float*)d_in[6];
  const float* v0  = (const float*)d_in[7];
  const float* m0  = (const float*)d_in[8];

  float* out  = (float*)d_out;
  float* lout = out;
  float* hout = out + (size_t)BB * SEQL * HID;
  float* cout = hout + (size_t)BB * HID;   // running c
  float* vout = cout + (size_t)BB * HID;   // running v
  float* mout = vout + (size_t)BB * GG;    // running m

  char* ws = (char*)d_ws;
  size_t o = 0;
  _Float16* wih_hi = (_Float16*)(ws + o); o += (size_t)GG * INF * 2;
  _Float16* wih_lo = (_Float16*)(ws + o); o += (size_t)GG * INF * 2;
  _Float16* whh_hi = (_Float16*)(ws + o); o += (size_t)GG * HID * 2;
  _Float16* whh_lo = (_Float16*)(ws + o); o += (size_t)GG * HID * 2;  // staging only
  _Float16* xs     = (_Float16*)(ws + o); o += (size_t)BB * SEQL * 2 * INF * 2;  // 64 MiB
  _Float16* hA     = (_Float16*)(ws + o); o += (size_t)BB * HID * 2;
  _Float16* hB     = (_Float16*)(ws + o); o += (size_t)BB * HID * 2;
  o = (o + 255) & ~(size_t)255;
  u32* flags = (u32*)(ws + o); o += (size_t)NWG_TOT * 32 * 4;
  float* U = (float*)(ws + o);

  const size_t STEP_BYTES = (size_t)BB * GG * sizeof(float);
  size_t cap = (ws_size > o) ? (ws_size - o) / STEP_BYTES : 1;
  if (cap < 1) cap = 1;
  int Tc = (int)(cap < (size_t)SEQL ? cap : (size_t)SEQL);

  split_x<<<(BB * SEQL * INF / 8) / 256, 256, 0, stream>>>(x, xs);
  transpose_split<<<dim3(GG / 32, INF / 32), 256, 0, stream>>>(wih, wih_hi, wih_lo, INF, GG);
  transpose_split<<<dim3(GG / 32, HID / 32), 256, 0, stream>>>(whh, whh_hi, whh_lo, HID, GG);
  init_state<<<(BB * GG) / 256, 256, 0, stream>>>(h0, c0, v0, m0, cout, vout, mout, hA);
  hipMemsetAsync(flags, 0, (size_t)NWG_TOT * 32 * 4, stream);

  for (int t0 = 0; t0 < SEQL; t0 += Tc) {
    int T = (SEQL - t0 < Tc) ? (SEQL - t0) : Tc;
    rnn_fused<<<NWG_TOT, NTHR, SMEM_BYTES, stream>>>(
        xs, wih_hi, wih_lo, bih, U, whh_hi, bhh,
        hA, hB, lout, hout, cout, vout, mout, flags, t0, T);
  }
}